// Round 3
// baseline (1326.217 us; speedup 1.0000x reference)
//
#include <hip/hip_runtime.h>

#define HW 128
#define KTAPS 255
#define DIMC 256

typedef short short8 __attribute__((ext_vector_type(8)));
typedef float f32x16 __attribute__((ext_vector_type(16)));

__device__ __forceinline__ short f2bf(float f) {
    return __builtin_bit_cast(short, (__bf16)f);
}
// Padded chunk addressing: 16B chunk index -> 16B slot (breaks 128B-stride bank collisions)
__device__ __forceinline__ int pad16(int c) { return c + (c >> 3); }

// Fragment layouts (v_mfma_f32_32x32x16_bf16):
//  A (MxK): elem(m,k): chunk=((m>>5)*8+(k>>4))*64 + (m&31)+32*((k>>3)&1), j=k&7
//  B (KxN): elem(k,n): chunk=((n>>5)*8+(k>>4))*64 + (n&31)+32*((k>>3)&1), j=k&7
//  C/D: col=lane&31, row=(reg&3)+8*(reg>>2)+4*(lane>>5)
//
// v4: one block per channel c (grid=256 -> exactly 1 block/CU, no tail).
//     1024 threads = 16 waves, each owns one 32x32 output tile (wm,wn).
//     All 10 batch slices processed in a software-pipelined loop:
//       - Toeplitz weight fragments live in VGPRs (64 taps/lane each matrix),
//         loaded ONCE, reused for all slices (kills per-slice weight staging).
//       - X(s+1) prefetched into registers at slice-s start; converted and
//         written to the ping-pong LDS buffer after mm2 (latency hidden).
//       - 2 barriers per slice. LDS: Px[2] (72KB) + Py (36KB) = 108KB.

__global__ __launch_bounds__(1024, 4)
void sep_conv255_mfma(const float* __restrict__ x,
                      const float* __restrict__ wh,
                      const float* __restrict__ bh,
                      const float* __restrict__ ww,
                      const float* __restrict__ bw,
                      float* __restrict__ out,
                      int nslices) {
    __shared__ __align__(16) short Px[2][2304 * 8];  // X bf16 frags, ping-pong (72 KB)
    __shared__ __align__(16) short Py[2304 * 8];     // Y bf16 frags (36 KB)

    const int c    = blockIdx.x;        // channel
    const int tid  = threadIdx.x;       // 0..1023
    const int lane = tid & 63;
    const int wv   = tid >> 6;          // wave 0..15
    const int wm   = wv >> 2;           // m-tile 0..3
    const int wn   = wv & 3;            // n-tile 0..3
    const int s31  = lane & 31;
    const int hi8  = (lane >> 5) << 3;

    const float* __restrict__ whc = wh + c * KTAPS;
    const float* __restrict__ wwc = ww + c * KTAPS;
    const float bhv = bh[c];
    const float bwv = bw[c];

    // X staging geometry: thread owns column xn, rows 16*xg .. 16*xg+15
    const int xn   = tid & 127;
    const int xg   = tid >> 7;                       // 0..7
    const int xch0 = (((xn >> 5) << 3) + xg) * 64 + (xn & 31);
    const size_t xoff = (size_t)(xg << 4) * HW + xn;

    // ---------------- prologue ----------------
    // slice-0 X loads
    float xv[16];
    {
        const float* xs = x + (size_t)c * (HW * HW);
#pragma unroll
        for (int i = 0; i < 16; ++i) xv[i] = xs[xoff + i * HW];
    }
    // Toeplitz weight fragments -> registers (reused for all slices)
    // A elem(m,k)=whc[127+k-m]; lane's frag[ks][j] = pa[16*ks+j],
    //   pa = whc + 127 + 8*hi - 32*wm - s31  (index range [0,254], always valid)
    // B elem(k,n)=wwc[127+k-n]; frag[ks][j] = pb[16*ks+j],
    //   pb = wwc + 127 + 8*hi - 32*wn - s31
    short8 wfa[8], wfb[8];
    {
        const float* pa = whc + (127 + hi8 - (wm << 5) - s31);
        const float* pb = wwc + (127 + hi8 - (wn << 5) - s31);
#pragma unroll
        for (int ks = 0; ks < 8; ++ks) {
#pragma unroll
            for (int j = 0; j < 8; ++j) {
                wfa[ks][j] = f2bf(pa[(ks << 4) + j]);
                wfb[ks][j] = f2bf(pb[(ks << 4) + j]);
            }
        }
    }
    // write slice-0 X frags
#pragma unroll
    for (int hh = 0; hh < 2; ++hh) {
        short8 v;
#pragma unroll
        for (int j = 0; j < 8; ++j) v[j] = f2bf(xv[(hh << 3) + j]);
        *reinterpret_cast<short8*>(&Px[0][pad16(xch0 + (hh << 5)) * 8]) = v;
    }
    __syncthreads();

    // repack constants: lane repacks Y column kk of its wave's 32x32 tile
    const int hbase = (wm << 5) + ((lane >> 5) << 2);
    const int kk    = (wn << 5) + s31;
    const int ycb   = ((wm << 3) + (kk >> 4)) * 64 + (((kk >> 3) & 1) << 5);
    const int yjj   = kk & 7;

    // ---------------- pipelined slice loop ----------------
    for (int s = 0; s < nslices; ++s) {
        const int  p   = s & 1;
        const bool pre = (s + 1 < nslices);

        // issue next-slice X loads early (latency hides under mm1+repack+mm2)
        if (pre) {
            const float* xs = x + ((size_t)(s + 1) * DIMC + c) * (HW * HW);
#pragma unroll
            for (int i = 0; i < 16; ++i) xv[i] = xs[xoff + i * HW];
        }

        // mm1: Y = Ah * X
        f32x16 acc;
#pragma unroll
        for (int j = 0; j < 16; ++j) acc[j] = 0.0f;
#pragma unroll
        for (int ks = 0; ks < 8; ++ks) {
            const short8 b = *reinterpret_cast<const short8*>(
                &Px[p][pad16(((wn << 3) + ks) * 64 + lane) * 8]);
            acc = __builtin_amdgcn_mfma_f32_32x32x16_bf16(wfa[ks], b, acc, 0, 0, 0);
        }

        // repack Y(+bh) -> Py as mm2 A-frags
#pragma unroll
        for (int r = 0; r < 16; ++r) {
            const int h = hbase + (r & 3) + ((r >> 2) << 3);
            Py[pad16(ycb + (h & 31)) * 8 + yjj] = f2bf(acc[r] + bhv);
        }
        __syncthreads();

        // mm2: Z = Y * Bw
#pragma unroll
        for (int j = 0; j < 16; ++j) acc[j] = 0.0f;
#pragma unroll
        for (int ks = 0; ks < 8; ++ks) {
            const short8 a = *reinterpret_cast<const short8*>(
                &Py[pad16(((wm << 3) + ks) * 64 + lane) * 8]);
            acc = __builtin_amdgcn_mfma_f32_32x32x16_bf16(a, wfb[ks], acc, 0, 0, 0);
        }

        // store Z + bw
        {
            float* zc = out + ((size_t)s * DIMC + c) * (HW * HW);
#pragma unroll
            for (int r = 0; r < 16; ++r) {
                const int h = hbase + (r & 3) + ((r >> 2) << 3);
                zc[(size_t)h * HW + kk] = acc[r] + bwv;
            }
        }

        // convert + write next-slice X frags into the other buffer
        if (pre) {
#pragma unroll
            for (int hh = 0; hh < 2; ++hh) {
                short8 v;
#pragma unroll
                for (int j = 0; j < 8; ++j) v[j] = f2bf(xv[(hh << 3) + j]);
                *reinterpret_cast<short8*>(&Px[p ^ 1][pad16(xch0 + (hh << 5)) * 8]) = v;
            }
        }
        __syncthreads();
    }
}

extern "C" void kernel_launch(void* const* d_in, const int* in_sizes, int n_in,
                              void* d_out, int out_size, void* d_ws, size_t ws_size,
                              hipStream_t stream) {
    const float* x  = (const float*)d_in[0];
    const float* wh = (const float*)d_in[1];
    const float* bh = (const float*)d_in[2];
    const float* ww = (const float*)d_in[3];
    const float* bw = (const float*)d_in[4];
    float* outp = (float*)d_out;

    const int nbatch = in_sizes[0] / (DIMC * HW * HW);  // = 10
    dim3 grid(DIMC);
    dim3 block(1024);
    hipLaunchKernelGGL(sep_conv255_mfma, grid, block, 0, stream,
                       x, wh, bh, ww, bw, outp, nbatch);
}

// Round 4
// 296.761 us; speedup vs baseline: 4.4690x; 4.4690x over previous
//
#include <hip/hip_runtime.h>

#define HW 128
#define KTAPS 255
#define DIMC 256

typedef short short8 __attribute__((ext_vector_type(8)));
typedef float f32x16 __attribute__((ext_vector_type(16)));

__device__ __forceinline__ short f2bf(float f) {
    return __builtin_bit_cast(short, (__bf16)f);
}
// Padded chunk addressing: 16B chunk index -> 16B slot (breaks 128B-stride bank collisions)
__device__ __forceinline__ int pad16(int c) { return c + (c >> 3); }

// Fragment layouts (v_mfma_f32_32x32x16_bf16):
//  A (MxK): elem(m,k): chunk=((m>>5)*8+(k>>4))*64 + (m&31)+32*((k>>3)&1), j=k&7
//  B (KxN): elem(k,n): chunk=((n>>5)*8+(k>>4))*64 + (n&31)+32*((k>>3)&1), j=k&7
//  C/D: col=lane&31, row=(reg&3)+8*(reg>>2)+4*(lane>>5)
//
// v5: v4's pipelined-slice structure, but weight fragments prebuilt in LDS
//     (NOT registers — v4's 64-VGPR weight residency spilled to scratch and
//     cost 3.5GB of HBM traffic). One block per channel (grid=256, 1 block/CU),
//     1024 threads = 16 waves, one 32x32 tile each. Per slice: 3 barriers.
//     LDS: Px 36K + Py 36K + Wa 36K + Wb 36K = 144 KB.

__global__ __launch_bounds__(1024, 4)
void sep_conv255_mfma(const float* __restrict__ x,
                      const float* __restrict__ wh,
                      const float* __restrict__ bh,
                      const float* __restrict__ ww,
                      const float* __restrict__ bw,
                      float* __restrict__ out,
                      int nslices) {
    __shared__ __align__(16) short Px[2304 * 8];  // X bf16 frags (36 KB)
    __shared__ __align__(16) short Py[2304 * 8];  // Y bf16 frags (36 KB)
    __shared__ __align__(16) short Wa[2304 * 8];  // Ah frags, built once (36 KB)
    __shared__ __align__(16) short Wb[2304 * 8];  // Bw frags, built once (36 KB)

    const int c    = blockIdx.x;        // channel
    const int tid  = threadIdx.x;       // 0..1023
    const int lane = tid & 63;
    const int wv   = tid >> 6;          // wave 0..15
    const int wm   = wv >> 2;           // m-tile 0..3
    const int wn   = wv & 3;            // n-tile 0..3
    const int s31  = lane & 31;

    const float* __restrict__ whc = wh + c * KTAPS;
    const float* __restrict__ wwc = ww + c * KTAPS;
    const float bhv = bh[c];
    const float bwv = bw[c];

    // X staging geometry: thread owns column xn, rows 16*xg .. 16*xg+15
    const int xn   = tid & 127;
    const int xg   = tid >> 7;                       // 0..7
    const int xch0 = (((xn >> 5) << 3) + xg) * 64 + (xn & 31);
    const size_t xoff = (size_t)(xg << 4) * HW + xn;

    // ---------------- prologue ----------------
    // slice-0 X loads issued first (latency hides under weight-frag build)
    float xv[16];
    {
        const float* xs = x + (size_t)c * (HW * HW);
#pragma unroll
        for (int i = 0; i < 16; ++i) xv[i] = xs[xoff + i * HW];
    }
    // Build Toeplitz weight frag matrices in LDS (once; reused all slices).
    // Ah elem(m,k) = whc[127+k-m]; Bw elem(k,n) = wwc[127+k-n]; idx in [0,254].
#pragma unroll
    for (int i = 0; i < 2; ++i) {
        const int ch = tid + (i << 10);          // chunk 0..2047
        const int lc = ch & 63;
        const int ks = (ch >> 6) & 7;
        const int tm = ch >> 9;
        const int m  = (tm << 5) + (lc & 31);
        const int kb = (ks << 4) + ((lc >> 5) << 3);
        const float* wpa = whc + (127 + kb - m);
        const float* wpb = wwc + (127 + kb - m);
        short8 va, vb;
#pragma unroll
        for (int j = 0; j < 8; ++j) { va[j] = f2bf(wpa[j]); vb[j] = f2bf(wpb[j]); }
        *reinterpret_cast<short8*>(&Wa[pad16(ch) * 8]) = va;
        *reinterpret_cast<short8*>(&Wb[pad16(ch) * 8]) = vb;
    }
    // write slice-0 X frags
#pragma unroll
    for (int hh = 0; hh < 2; ++hh) {
        short8 v;
#pragma unroll
        for (int j = 0; j < 8; ++j) v[j] = f2bf(xv[(hh << 3) + j]);
        *reinterpret_cast<short8*>(&Px[pad16(xch0 + (hh << 5)) * 8]) = v;
    }
    __syncthreads();

    // repack constants: lane repacks Y column kk of its wave's 32x32 tile
    const int hbase = (wm << 5) + ((lane >> 5) << 2);
    const int kk    = (wn << 5) + s31;
    const int ycb   = ((wm << 3) + (kk >> 4)) * 64 + (((kk >> 3) & 1) << 5);
    const int yjj   = kk & 7;

    // ---------------- pipelined slice loop ----------------
    for (int s = 0; s < nslices; ++s) {
        const bool pre = (s + 1 < nslices);

        // issue next-slice X loads early (latency hides under mm1)
        if (pre) {
            const float* xs = x + ((size_t)(s + 1) * DIMC + c) * (HW * HW);
#pragma unroll
            for (int i = 0; i < 16; ++i) xv[i] = xs[xoff + i * HW];
        }

        // mm1: Y = Ah * X
        f32x16 acc;
#pragma unroll
        for (int j = 0; j < 16; ++j) acc[j] = 0.0f;
#pragma unroll
        for (int ks = 0; ks < 8; ++ks) {
            const short8 a = *reinterpret_cast<const short8*>(
                &Wa[pad16(((wm << 3) + ks) * 64 + lane) * 8]);
            const short8 b = *reinterpret_cast<const short8*>(
                &Px[pad16(((wn << 3) + ks) * 64 + lane) * 8]);
            acc = __builtin_amdgcn_mfma_f32_32x32x16_bf16(a, b, acc, 0, 0, 0);
        }
        __syncthreads();   // Px reads done; Py safe to overwrite

        // repack Y(+bh) -> Py as mm2 A-frags; stage X(s+1) -> Px
#pragma unroll
        for (int r = 0; r < 16; ++r) {
            const int h = hbase + (r & 3) + ((r >> 2) << 3);
            Py[pad16(ycb + (h & 31)) * 8 + yjj] = f2bf(acc[r] + bhv);
        }
        if (pre) {
#pragma unroll
            for (int hh = 0; hh < 2; ++hh) {
                short8 v;
#pragma unroll
                for (int j = 0; j < 8; ++j) v[j] = f2bf(xv[(hh << 3) + j]);
                *reinterpret_cast<short8*>(&Px[pad16(xch0 + (hh << 5)) * 8]) = v;
            }
        }
        __syncthreads();   // Py + Px(s+1) visible

        // mm2: Z = Y * Bw
#pragma unroll
        for (int j = 0; j < 16; ++j) acc[j] = 0.0f;
#pragma unroll
        for (int ks = 0; ks < 8; ++ks) {
            const short8 a = *reinterpret_cast<const short8*>(
                &Py[pad16(((wm << 3) + ks) * 64 + lane) * 8]);
            const short8 b = *reinterpret_cast<const short8*>(
                &Wb[pad16(((wn << 3) + ks) * 64 + lane) * 8]);
            acc = __builtin_amdgcn_mfma_f32_32x32x16_bf16(a, b, acc, 0, 0, 0);
        }

        // store Z + bw
        {
            float* zc = out + ((size_t)s * DIMC + c) * (HW * HW);
#pragma unroll
            for (int r = 0; r < 16; ++r) {
                const int h = hbase + (r & 3) + ((r >> 2) << 3);
                zc[(size_t)h * HW + kk] = acc[r] + bwv;
            }
        }
        __syncthreads();   // Py reads done before next repack
    }
}

extern "C" void kernel_launch(void* const* d_in, const int* in_sizes, int n_in,
                              void* d_out, int out_size, void* d_ws, size_t ws_size,
                              hipStream_t stream) {
    const float* x  = (const float*)d_in[0];
    const float* wh = (const float*)d_in[1];
    const float* bh = (const float*)d_in[2];
    const float* ww = (const float*)d_in[3];
    const float* bw = (const float*)d_in[4];
    float* outp = (float*)d_out;

    const int nbatch = in_sizes[0] / (DIMC * HW * HW);  // = 10
    dim3 grid(DIMC);
    dim3 block(1024);
    hipLaunchKernelGGL(sep_conv255_mfma, grid, block, 0, stream,
                       x, wh, bh, ww, bw, outp, nbatch);
}

// Round 5
// 296.715 us; speedup vs baseline: 4.4697x; 1.0002x over previous
//
#include <hip/hip_runtime.h>

#define HW 128
#define KTAPS 255
#define DIMC 256

typedef short short8 __attribute__((ext_vector_type(8)));
typedef float f32x16 __attribute__((ext_vector_type(16)));

__device__ __forceinline__ short f2bf(float f) {
    return __builtin_bit_cast(short, (__bf16)f);
}
// Padded chunk addressing: 16B chunk index -> 16B slot (breaks 128B-stride bank collisions)
__device__ __forceinline__ int pad16(int c) { return c + (c >> 3); }

// LDS-only barrier: waits ds ops for visibility but does NOT drain vmcnt,
// so global stores/loads stay in flight across it (T4: counted waits).
__device__ __forceinline__ void bar_lds() {
    asm volatile("s_waitcnt lgkmcnt(0)" ::: "memory");
    __builtin_amdgcn_s_barrier();
}

// Fragment layouts (v_mfma_f32_32x32x16_bf16):
//  A (MxK): elem(m,k): chunk=((m>>5)*8+(k>>4))*64 + (m&31)+32*((k>>3)&1), j=k&7
//  B (KxN): elem(k,n): chunk=((n>>5)*8+(k>>4))*64 + (n&31)+32*((k>>3)&1), j=k&7
//  C/D: col=lane&31, row=(reg&3)+8*(reg>>2)+4*(lane>>5)
//
// v6: v5's structure + no-drain barriers + Px double-buffer.
//  - Toeplitz frag tiles dedup'd: content depends only on d=16ks-32wm (14
//    distinct tiles per matrix) -> 28KB weight bank instead of 72KB.
//  - LDS: Px[2] 72K + Py 36K + WB 28K = 136KB, 1 block/CU (grid=256).
//  - Loads for slice s+2 issued BEFORE stores of slice s (queue order), so the
//    compiler's dependency wait at the X->LDS write is a counted vmcnt(16):
//    stores keep streaming; read+write overlap in the HBM pipe.

__global__ __launch_bounds__(1024, 4)
void sep_conv255_mfma(const float* __restrict__ x,
                      const float* __restrict__ wh,
                      const float* __restrict__ bh,
                      const float* __restrict__ ww,
                      const float* __restrict__ bw,
                      float* __restrict__ out,
                      int nslices) {
    __shared__ __align__(16) short Px[2][2304 * 8];  // X bf16 frags, ping-pong (72 KB)
    __shared__ __align__(16) short Py[2304 * 8];     // Y bf16 frags (36 KB)
    __shared__ __align__(16) short WB[1792 * 8];     // Toeplitz tile bank (28 KB)
                                                     //  tiles 0..13: Ah (d=16t-96)
                                                     //  tiles 14..27: Bw

    const int c    = blockIdx.x;        // channel
    const int tid  = threadIdx.x;       // 0..1023
    const int lane = tid & 63;
    const int wv   = tid >> 6;          // wave 0..15
    const int wm   = wv >> 2;           // m-tile 0..3
    const int wn   = wv & 3;            // n-tile 0..3
    const int s31  = lane & 31;

    const float* __restrict__ whc = wh + c * KTAPS;
    const float* __restrict__ wwc = ww + c * KTAPS;
    const float bhv = bh[c];
    const float bwv = bw[c];

    // X staging geometry: thread owns column xn, rows 16*xg .. 16*xg+15
    const int xn   = tid & 127;
    const int xg   = tid >> 7;                       // 0..7
    const int xch0 = (((xn >> 5) << 3) + xg) * 64 + (xn & 31);
    const size_t xoff = (size_t)(xg << 4) * HW + xn;

    // ---------------- prologue ----------------
    float xv[16];
    {   // slice-0 X loads issued first
        const float* xs = x + (size_t)c * (HW * HW);
#pragma unroll
        for (int i = 0; i < 16; ++i) xv[i] = xs[xoff + i * HW];
    }
    // Build dedup'd Toeplitz tile bank.
    // Tile t (Ah): lane lc, elem j = whc[31 + 16t + 8*(lc>>5) - (lc&31) + j]  (in [0,254])
#pragma unroll
    for (int i = 0; i < 2; ++i) {
        const int ch = tid + (i << 10);
        if (ch < 1792) {
            const int isB = (ch >= 896);
            const int lc  = ch & 63;
            const int t   = (ch >> 6) - (isB ? 14 : 0);
            const float* ws = isB ? wwc : whc;
            const float* wp = ws + (31 + (t << 4) + ((lc >> 5) << 3) - (lc & 31));
            short8 v;
#pragma unroll
            for (int j = 0; j < 8; ++j) v[j] = f2bf(wp[j]);
            *reinterpret_cast<short8*>(&WB[ch * 8]) = v;
        }
    }
    // write slice-0 X frags (compiler inserts counted vmcnt for xv)
#pragma unroll
    for (int hh = 0; hh < 2; ++hh) {
        short8 v;
#pragma unroll
        for (int j = 0; j < 8; ++j) v[j] = f2bf(xv[(hh << 3) + j]);
        *reinterpret_cast<short8*>(&Px[0][pad16(xch0 + (hh << 5)) * 8]) = v;
    }
    // issue slice-1 loads (consumed at E of slice 0)
    if (1 < nslices) {
        const float* xs = x + ((size_t)DIMC + c) * (HW * HW);
#pragma unroll
        for (int i = 0; i < 16; ++i) xv[i] = xs[xoff + i * HW];
    }
    bar_lds();

    // repack constants: lane repacks Y column kk of its wave's 32x32 tile
    const int hbase = (wm << 5) + ((lane >> 5) << 2);
    const int kk    = (wn << 5) + s31;
    const int ycb   = ((wm << 3) + (kk >> 4)) * 64 + (((kk >> 3) & 1) << 5);
    const int yjj   = kk & 7;

    // ---------------- pipelined slice loop ----------------
    for (int s = 0; s < nslices; ++s) {
        const int p = s & 1;

        // mm1: Y = Ah * X   (A from tile bank: t = ks - 2*wm + 6)
        f32x16 acc;
#pragma unroll
        for (int j = 0; j < 16; ++j) acc[j] = 0.0f;
#pragma unroll
        for (int ks = 0; ks < 8; ++ks) {
            const short8 a = *reinterpret_cast<const short8*>(
                &WB[(((ks - (wm << 1) + 6) << 6) + lane) * 8]);
            const short8 b = *reinterpret_cast<const short8*>(
                &Px[p][pad16(((wn << 3) + ks) * 64 + lane) * 8]);
            acc = __builtin_amdgcn_mfma_f32_32x32x16_bf16(a, b, acc, 0, 0, 0);
        }

        // repack Y(+bh) -> Py as mm2 A-frags
#pragma unroll
        for (int r = 0; r < 16; ++r) {
            const int h = hbase + (r & 3) + ((r >> 2) << 3);
            Py[pad16(ycb + (h & 31)) * 8 + yjj] = f2bf(acc[r] + bhv);
        }

        // E: stage X(s+1) -> Px[p^1]. Loads were issued ~1 slice ago and are
        // OLDER than the in-flight stores -> compiler emits counted vmcnt,
        // leaving stores streaming.
        if (s + 1 < nslices) {
#pragma unroll
            for (int hh = 0; hh < 2; ++hh) {
                short8 v;
#pragma unroll
                for (int j = 0; j < 8; ++j) v[j] = f2bf(xv[(hh << 3) + j]);
                *reinterpret_cast<short8*>(&Px[p ^ 1][pad16(xch0 + (hh << 5)) * 8]) = v;
            }
        }
        bar_lds();   // F: Py + Px(s+1) visible; stores still in flight

        // issue loads(s+2) BEFORE this slice's stores (queue order: loads first)
        if (s + 2 < nslices) {
            const float* xs = x + ((size_t)(s + 2) * DIMC + c) * (HW * HW);
#pragma unroll
            for (int i = 0; i < 16; ++i) xv[i] = xs[xoff + i * HW];
        }

        // mm2: Z = Y * Bw   (B from tile bank: tile 14 + ks - 2*wn + 6)
#pragma unroll
        for (int j = 0; j < 16; ++j) acc[j] = 0.0f;
#pragma unroll
        for (int ks = 0; ks < 8; ++ks) {
            const short8 a = *reinterpret_cast<const short8*>(
                &Py[pad16(((wm << 3) + ks) * 64 + lane) * 8]);
            const short8 b = *reinterpret_cast<const short8*>(
                &WB[(((ks - (wn << 1) + 20) << 6) + lane) * 8]);
            acc = __builtin_amdgcn_mfma_f32_32x32x16_bf16(a, b, acc, 0, 0, 0);
        }

        // stores (fire-and-forget; never drained by our barriers)
        {
            float* zc = out + ((size_t)s * DIMC + c) * (HW * HW);
#pragma unroll
            for (int r = 0; r < 16; ++r) {
                const int h = hbase + (r & 3) + ((r >> 2) << 3);
                zc[(size_t)h * HW + kk] = acc[r] + bwv;
            }
        }
        bar_lds();   // I: mm2's Py reads retired; next repack may overwrite
    }
}

extern "C" void kernel_launch(void* const* d_in, const int* in_sizes, int n_in,
                              void* d_out, int out_size, void* d_ws, size_t ws_size,
                              hipStream_t stream) {
    const float* x  = (const float*)d_in[0];
    const float* wh = (const float*)d_in[1];
    const float* bh = (const float*)d_in[2];
    const float* ww = (const float*)d_in[3];
    const float* bw = (const float*)d_in[4];
    float* outp = (float*)d_out;

    const int nbatch = in_sizes[0] / (DIMC * HW * HW);  // = 10
    dim3 grid(DIMC);
    dim3 block(1024);
    hipLaunchKernelGGL(sep_conv255_mfma, grid, block, 0, stream,
                       x, wh, bh, ww, bw, outp, nbatch);
}

// Round 6
// 291.102 us; speedup vs baseline: 4.5559x; 1.0193x over previous
//
#include <hip/hip_runtime.h>

#define HW 128
#define KTAPS 255
#define DIMC 256

typedef short short8  __attribute__((ext_vector_type(8)));
typedef short short4v __attribute__((ext_vector_type(4)));
typedef float f32x16  __attribute__((ext_vector_type(16)));
typedef float f32x4   __attribute__((ext_vector_type(4)));

__device__ __forceinline__ short f2bf(float f) {
    return __builtin_bit_cast(short, (__bf16)f);
}
// Padded chunk addressing: 16B chunk index -> 16B slot
__device__ __forceinline__ int pad16(int c) { return c + (c >> 3); }

// LDS-only barrier: does NOT drain vmcnt (global loads/stores stay in flight)
__device__ __forceinline__ void bar_lds() {
    asm volatile("s_waitcnt lgkmcnt(0)" ::: "memory");
    __builtin_amdgcn_s_barrier();
}

// Fragment layouts (v_mfma_f32_32x32x16_bf16):
//  A (MxK): elem(m,k): chunk=((m>>5)*8+(k>>4))*64 + (m&31)+32*((k>>3)&1), j=k&7
//  B (KxN): elem(k,n): chunk=((n>>5)*8+(k>>4))*64 + (n&31)+32*((k>>3)&1), j=k&7
//  C/D: col=lane&31, row=(reg&3)+8*(reg>>2)+4*(lane>>5)
//
// v7: COMMUTED convs to unlock 16B/lane global access (the 2.4 TB/s wall was
//     scalar 4B VMEM width — every prior schedule pinned there).
//       Z = Ah·(X·Bw) + bh*sw[w] + bw,  sw[w] = sum_k Bw[k,w]  (prefix of ww)
//     mm1: W = X·Bw — A-operand = X, K = image COLUMNS (contiguous axis):
//          A-frag 16B = 8 consecutive floats of a row = 2 float4 loads, direct.
//     mm2: Z = Ah·W — both Toeplitz banks (28KB) built once, reused 10 slices.
//     Store: Z transposed via 33KB LDS f32 buffer (2 half-image rounds) ->
//          coalesced float4 stores (1KB/wave-instr).
//     LDS: PxA 36K + Py 36K + WB 28K + Zt 33K + cw 0.5K = 137KB, 1 block/CU.

__global__ __launch_bounds__(1024, 4)
void sep_conv255_mfma(const float* __restrict__ x,
                      const float* __restrict__ wh,
                      const float* __restrict__ bh,
                      const float* __restrict__ ww,
                      const float* __restrict__ bw,
                      float* __restrict__ out,
                      int nslices) {
    __shared__ __align__(16) short PxA[2304 * 8];  // X as mm1 A-frags (36 KB)
    __shared__ __align__(16) short Py [2304 * 8];  // W as mm2 B-frags (36 KB)
    __shared__ __align__(16) short WB [1792 * 8];  // Toeplitz tiles: 0..13 Ah, 14..27 Bw (28 KB)
    __shared__ __align__(16) float Zt [64 * 132];  // Z transpose buffer (33 KB)
    __shared__ float cw[HW];                       // fused per-column bias (512 B)

    const int c    = blockIdx.x;        // channel
    const int tid  = threadIdx.x;       // 0..1023
    const int lane = tid & 63;
    const int wv   = tid >> 6;          // wave 0..15
    const int wm   = wv >> 2;           // m-tile 0..3 (output rows)
    const int wn   = wv & 3;            // n-tile 0..3 (output cols)
    const int s31  = lane & 31;
    const int hi   = lane >> 5;

    const float* __restrict__ whc = wh + c * KTAPS;
    const float* __restrict__ wwc = ww + c * KTAPS;

    // X geometry: thread owns cols 4*tw..4*tw+3, rows bh0+32i (i=0..3)
    const int tw  = tid & 31;
    const int bh0 = tid >> 5;           // 0..31
    int stChunk[4];
#pragma unroll
    for (int i = 0; i < 4; ++i)
        stChunk[i] = ((i << 3) + (tw >> 2)) * 64 + bh0 + (((tw >> 1) & 1) << 5);
    const int stOff = (tw & 1) << 2;    // short offset within 16B chunk
    const size_t ldOff = (size_t)bh0 * HW + (tw << 2);

    // ---------------- prologue ----------------
    f32x4 xv[4];
    {   // slice-0 loads first (hide under WB/cw build)
        const float* xs = x + (size_t)c * (HW * HW);
#pragma unroll
        for (int i = 0; i < 4; ++i)
            xv[i] = *reinterpret_cast<const f32x4*>(&xs[ldOff + (size_t)(i << 5) * HW]);
    }
    // Toeplitz tile bank: tile t, lane lc, elem j = taps[31+16t+8*(lc>>5)-(lc&31)+j]
#pragma unroll
    for (int i = 0; i < 2; ++i) {
        const int ch = tid + (i << 10);
        if (ch < 1792) {
            const int isB = (ch >= 896);
            const int lc  = ch & 63;
            const int t   = (ch >> 6) - (isB ? 14 : 0);
            const float* ws = isB ? wwc : whc;
            const float* wp = ws + (31 + (t << 4) + ((lc >> 5) << 3) - (lc & 31));
            short8 v;
#pragma unroll
            for (int j = 0; j < 8; ++j) v[j] = f2bf(wp[j]);
            *reinterpret_cast<short8*>(&WB[ch * 8]) = v;
        }
    }
    // fused bias: cw[w] = bh * sum_k Bw[k,w] + bw ; Bw[k,w] = ww[127+k-w]
    if (tid < HW) {
        float s = 0.0f;
        for (int i = 0; i < HW; ++i) s += wwc[127 - tid + i];
        cw[tid] = bh[c] * s + bw[c];
    }
    // stage slice-0 X (b64 frag-half writes; counted vmcnt on xv)
#pragma unroll
    for (int i = 0; i < 4; ++i) {
        short4v v;
#pragma unroll
        for (int j = 0; j < 4; ++j) v[j] = f2bf(xv[i][j]);
        *reinterpret_cast<short4v*>(&PxA[pad16(stChunk[i]) * 8 + stOff]) = v;
    }
    // issue slice-1 loads
    if (1 < nslices) {
        const float* xs = x + ((size_t)DIMC + c) * (HW * HW);
#pragma unroll
        for (int i = 0; i < 4; ++i)
            xv[i] = *reinterpret_cast<const f32x4*>(&xs[ldOff + (size_t)(i << 5) * HW]);
    }
    bar_lds();

    const int   kk     = (wn << 5) + s31;                     // output column w
    const float cwv    = cw[kk];
    const int   hbase  = (wm << 5) + (hi << 2);
    const int   rpBase = ((wn << 3) + (wm << 1)) * 64 + s31;  // repack chunk base

    // ---------------- pipelined slice loop ----------------
    for (int s = 0; s < nslices; ++s) {
        // mm1: W = X * Bw   (A = X frags, B = Bw tiles 14 + ks - 2wn + 6)
        f32x16 acc;
#pragma unroll
        for (int j = 0; j < 16; ++j) acc[j] = 0.0f;
#pragma unroll
        for (int ks = 0; ks < 8; ++ks) {
            const short8 a = *reinterpret_cast<const short8*>(
                &PxA[pad16(((wm << 3) + ks) * 64 + lane) * 8]);
            const short8 b = *reinterpret_cast<const short8*>(
                &WB[(((ks - (wn << 1) + 20) << 6) + lane) * 8]);
            acc = __builtin_amdgcn_mfma_f32_32x32x16_bf16(a, b, acc, 0, 0, 0);
        }
        // repack W -> Py as mm2 B-frags: elem(k=h', n=w)
        //   h' = 32wm + 4hi + (r&3) + 8(r>>2) -> chunk = rpBase + 64*(r>>3) + 32*((r>>2)&1)
#pragma unroll
        for (int r = 0; r < 16; ++r) {
            const int chunk = rpBase + ((r >> 3) << 6) + (((r >> 2) & 1) << 5);
            const int j     = (hi << 2) + (r & 3);
            Py[pad16(chunk) * 8 + j] = f2bf(acc[r]);
        }
        bar_lds();  // A: PxA reads done, Py visible

        // stage X(s+1) into PxA; then reissue loads(s+2) into xv
        if (s + 1 < nslices) {
#pragma unroll
            for (int i = 0; i < 4; ++i) {
                short4v v;
#pragma unroll
                for (int j = 0; j < 4; ++j) v[j] = f2bf(xv[i][j]);
                *reinterpret_cast<short4v*>(&PxA[pad16(stChunk[i]) * 8 + stOff]) = v;
            }
        }
        if (s + 2 < nslices) {
            const float* xs = x + ((size_t)(s + 2) * DIMC + c) * (HW * HW);
#pragma unroll
            for (int i = 0; i < 4; ++i)
                xv[i] = *reinterpret_cast<const f32x4*>(&xs[ldOff + (size_t)(i << 5) * HW]);
        }

        // mm2: Z = Ah * W   (A = Ah tiles ks - 2wm + 6, B = W frags)
#pragma unroll
        for (int j = 0; j < 16; ++j) acc[j] = 0.0f;
#pragma unroll
        for (int ks = 0; ks < 8; ++ks) {
            const short8 a = *reinterpret_cast<const short8*>(
                &WB[(((ks - (wm << 1) + 6) << 6) + lane) * 8]);
            const short8 b = *reinterpret_cast<const short8*>(
                &Py[pad16(((wn << 3) + ks) * 64 + lane) * 8]);
            acc = __builtin_amdgcn_mfma_f32_32x32x16_bf16(a, b, acc, 0, 0, 0);
        }

        float* zc = out + ((size_t)s * DIMC + c) * (HW * HW);

        // epilogue: transpose Z through Zt in 2 half-image rounds -> float4 stores
        if (wm < 2) {     // rows 0..63
#pragma unroll
            for (int r = 0; r < 16; ++r) {
                const int h = hbase + (r & 3) + ((r >> 2) << 3);
                Zt[h * 132 + kk] = acc[r] + cwv;
            }
        }
        bar_lds();  // B: Zt half0 ready
#pragma unroll
        for (int i = 0; i < 2; ++i) {
            const int hh = bh0 + (i << 5);
            const f32x4 v = *reinterpret_cast<const f32x4*>(&Zt[hh * 132 + (tw << 2)]);
            *reinterpret_cast<f32x4*>(&zc[(size_t)hh * HW + (tw << 2)]) = v;
        }
        bar_lds();  // C: half0 reads retired
        if (wm >= 2) {    // rows 64..127
#pragma unroll
            for (int r = 0; r < 16; ++r) {
                const int h = hbase + (r & 3) + ((r >> 2) << 3);
                Zt[(h - 64) * 132 + kk] = acc[r] + cwv;
            }
        }
        bar_lds();  // D: Zt half1 ready
#pragma unroll
        for (int i = 0; i < 2; ++i) {
            const int hh = bh0 + (i << 5);
            const f32x4 v = *reinterpret_cast<const f32x4*>(&Zt[hh * 132 + (tw << 2)]);
            *reinterpret_cast<f32x4*>(&zc[(size_t)(64 + hh) * HW + (tw << 2)]) = v;
        }
        // Zt half1 reads retire at next slice's barrier A before any rewrite.
    }
}

extern "C" void kernel_launch(void* const* d_in, const int* in_sizes, int n_in,
                              void* d_out, int out_size, void* d_ws, size_t ws_size,
                              hipStream_t stream) {
    const float* x  = (const float*)d_in[0];
    const float* wh = (const float*)d_in[1];
    const float* bh = (const float*)d_in[2];
    const float* ww = (const float*)d_in[3];
    const float* bw = (const float*)d_in[4];
    float* outp = (float*)d_out;

    const int nbatch = in_sizes[0] / (DIMC * HW * HW);  // = 10
    dim3 grid(DIMC);
    dim3 block(1024);
    hipLaunchKernelGGL(sep_conv255_mfma, grid, block, 0, stream,
                       x, wh, bh, ww, bw, outp, nbatch);
}